// Round 12
// baseline (163.702 us; speedup 1.0000x reference)
//
#include <hip/hip_runtime.h>
#include <hip/hip_fp16.h>
#include <math.h>

// ---- problem constants (match reference) ----
#define NNODES 8704          // B*K = 512*17
#define NEDGE  139264
#define EPLUS  (NEDGE + NNODES)   // 147968 (self-loops appended)
#define NEG_SLOPE 0.2f
#define DEGCAP 64            // fixed CSR slot capacity; deg = Poisson(16)+1, P(>64) ~ 2e-14
#define LDSK2  72            // gemm LDS row stride for BK=64 (64 + 8 pad halves); frag reads 2-way

#define NB_PV  16            // prep kernel: pvec blocks
#define NB_WC  512           // prep kernel: wcat blocks (8x8x8 flattened)
#define NB_SC  ((EPLUS + 255) / 256)   // scatter blocks (579)
#define NB_AL  (NNODES / 4)  // alpha blocks (2176)

typedef _Float16 f16x8 __attribute__((ext_vector_type(8)));
typedef _Float16 f16x4 __attribute__((ext_vector_type(4)));
typedef float    f32x4 __attribute__((ext_vector_type(4)));

__device__ __forceinline__ float lrelu(float v) { return v >= 0.f ? v : NEG_SLOPE * v; }

// ---------------- K1: p-vectors (+zero cnt/alphasB) and Wcat^T, one kernel ----------------
__global__ __launch_bounds__(256) void prep_all(const float* __restrict__ W1,
                                                const float* __restrict__ as1,
                                                const float* __restrict__ ad1,
                                                const float* __restrict__ W2,
                                                const float* __restrict__ as2,
                                                const float* __restrict__ ad2,
                                                float* __restrict__ pbuf,
                                                int* __restrict__ cnt,
                                                float* __restrict__ alphasB,
                                                _Float16* __restrict__ Wc1,
                                                _Float16* __restrict__ Wc2) {
    __shared__ float tile[32][33];
    const int b = blockIdx.x;
    const int t = threadIdx.x;
    if (b < NB_PV) {
        // p[b][k] = sum_c W[k][h*256+c]*a[h][c];  b = layer*8 + sd*4 + h
        for (int i = b * 256 + t; i < NNODES; i += NB_PV * 256) cnt[i] = 0;
        for (int i = b * 256 + t; i < NNODES * 8; i += NB_PV * 256) alphasB[i] = 0.f;
        float* a_sh = &tile[0][0];
        const int layer = b >> 3, sd = (b >> 2) & 1, h = b & 3;
        const float* W  = layer ? W2 : W1;
        const float* av = layer ? (sd ? ad2 : as2) : (sd ? ad1 : as1);
        a_sh[t] = av[h * 256 + t];
        __syncthreads();
        float acc = 0.f;
        const float* Wr = W + (size_t)t * 1024 + h * 256;
#pragma unroll 8
        for (int c = 0; c < 256; ++c) acc += Wr[c] * a_sh[c];
        pbuf[b * 256 + t] = acc;
    } else {
        // Wcatt[o][h*256+k] = W[k][h*256+o] (fp16)
        const int idx = b - NB_PV;                 // 0..511
        const int k0 = (idx & 7) * 32, o0 = ((idx >> 3) & 7) * 32;
        const int z = idx >> 6;                    // 0..7
        const int layer = z >> 2, h = z & 3;
        const float* W = layer ? W2 : W1;
        _Float16* Wc   = layer ? Wc2 : Wc1;
#pragma unroll
        for (int p = 0; p < 4; ++p) {
            int e = t + p * 256; int kk = e >> 5, oo = e & 31;
            tile[kk][oo] = W[(size_t)(k0 + kk) * 1024 + h * 256 + o0 + oo];
        }
        __syncthreads();
#pragma unroll
        for (int p = 0; p < 4; ++p) {
            int e = t + p * 256; int oo = e >> 5, kk = e & 31;
            Wc[(size_t)(o0 + oo) * 1024 + h * 256 + k0 + kk] = (_Float16)tile[kk][oo];
        }
    }
}

// ---------------- K2: edge scatter + layer-1 alpha dots, one kernel ----------------
__global__ __launch_bounds__(256) void scatter_alpha(const int* __restrict__ ei,
                                                     int* __restrict__ cnt,
                                                     int* __restrict__ csr,
                                                     const float* __restrict__ xf,
                                                     _Float16* __restrict__ xh_out,
                                                     const float* __restrict__ p /* [8][256] */,
                                                     float* __restrict__ asrc,
                                                     float* __restrict__ adst) {
    const int b = blockIdx.x;
    const int t = threadIdx.x;
    if (b < NB_SC) {
        int e = b * 256 + t;
        if (e >= EPLUS) return;
        int src, dst;
        if (e < NEDGE) { src = ei[e]; dst = ei[NEDGE + e]; }
        else           { src = dst = e - NEDGE; }
        int slot = atomicAdd(&cnt[dst], 1);
        if (slot < DEGCAP) csr[dst * DEGCAP + slot] = src;
    } else {
        const int wave = t >> 6, l = t & 63;
        const int n = (b - NB_SC) * 4 + wave;
        float4 pv[8];
#pragma unroll
        for (int v = 0; v < 8; ++v) pv[v] = *(const float4*)(p + v * 256 + l * 4);
        float4 xv = *(const float4*)(xf + (size_t)n * 256 + l * 4);
        f16x4 hv = {(_Float16)xv.x, (_Float16)xv.y, (_Float16)xv.z, (_Float16)xv.w};
        *(f16x4*)(xh_out + (size_t)n * 256 + l * 4) = hv;
        float d[8];
#pragma unroll
        for (int v = 0; v < 8; ++v)
            d[v] = xv.x * pv[v].x + xv.y * pv[v].y + xv.z * pv[v].z + xv.w * pv[v].w;
#pragma unroll
        for (int off = 1; off <= 32; off <<= 1)
#pragma unroll
            for (int v = 0; v < 8; ++v) d[v] += __shfl_xor(d[v], off);
        if (l == 0) {
            *(float4*)(asrc + n * 4) = make_float4(d[0], d[1], d[2], d[3]);
            *(float4*)(adst + n * 4) = make_float4(d[4], d[5], d[6], d[7]);
        }
    }
}

// ---------------- softmax + x-gather, barrier-free: wave = node ----------------
__global__ __launch_bounds__(256) void agg_gather(const _Float16* __restrict__ xh,
                                                  const int* __restrict__ cnt,
                                                  const int* __restrict__ csr,
                                                  const float* __restrict__ asrc,
                                                  const float* __restrict__ adst,
                                                  _Float16* __restrict__ y) {
    const int w = threadIdx.x >> 6, l = threadIdx.x & 63;
    const int n = blockIdx.x * 4 + w;
    int deg = cnt[n]; if (deg > DEGCAP) deg = DEGCAP;

    float4 ad = *(const float4*)(adst + n * 4);
    int src_l = 0;
    float w0 = 0.f, w1 = 0.f, w2 = 0.f, w3 = 0.f;
    if (l < deg) {
        src_l = csr[n * DEGCAP + l];
        float4 as = *(const float4*)(asrc + src_l * 4);
        w0 = __expf(lrelu(as.x + ad.x));
        w1 = __expf(lrelu(as.y + ad.y));
        w2 = __expf(lrelu(as.z + ad.z));
        w3 = __expf(lrelu(as.w + ad.w));
    }
    float d0 = w0, d1 = w1, d2 = w2, d3 = w3;
#pragma unroll
    for (int off = 32; off >= 1; off >>= 1) {
        d0 += __shfl_xor(d0, off);
        d1 += __shfl_xor(d1, off);
        d2 += __shfl_xor(d2, off);
        d3 += __shfl_xor(d3, off);
    }
    w0 /= d0; w1 /= d1; w2 /= d2; w3 /= d3;   // normalized weight of slot l

    float acc[4][4] = {};   // [ch_sub][head]
    for (int s = 0; s < deg; ++s) {
        int src = __shfl(src_l, s);
        float u0 = __shfl(w0, s), u1 = __shfl(w1, s);
        float u2 = __shfl(w2, s), u3 = __shfl(w3, s);
        f16x4 xv = *(const f16x4*)(xh + (size_t)src * 256 + l * 4);
#pragma unroll
        for (int j = 0; j < 4; ++j) {
            float v = (float)xv[j];
            acc[j][0] += u0 * v; acc[j][1] += u1 * v;
            acc[j][2] += u2 * v; acc[j][3] += u3 * v;
        }
    }
#pragma unroll
    for (int h = 0; h < 4; ++h) {
        f16x4 pv = {(_Float16)acc[0][h], (_Float16)acc[1][h],
                    (_Float16)acc[2][h], (_Float16)acc[3][h]};
        *(f16x4*)(y + (size_t)n * 1024 + h * 256 + l * 4) = pv;
    }
}

// ---------------- output GEMM v3: out = 0.25 * Y[8704,1024] @ Wcatt^T + bias ----------------
// 512 threads (8 waves 2x4), BM=64, BN=128, BK=64; grid (NNODES/64, 2) = 272 blocks
// -> every CU busy, 2 waves/SIMD. Wave tile 32x32 (2x2 frags), 8 MFMA/step.
// If p2 != null: fused layer-2 alpha dots -> atomicAdd into asrc2/adst2.
__global__ __launch_bounds__(512) void gemm_out(const _Float16* __restrict__ Y,
                                                const _Float16* __restrict__ Wcatt,
                                                const float* __restrict__ bias,
                                                const float* __restrict__ p2,
                                                _Float16* __restrict__ outH,  // relu+fp16 if non-null
                                                float* __restrict__ outF,
                                                float* __restrict__ asrc2,
                                                float* __restrict__ adst2) {
    __shared__ __align__(16) _Float16 As[64 * LDSK2];     // 9.2 KB
    __shared__ __align__(16) _Float16 Bs[128 * LDSK2];    // 18.4 KB
    __shared__ float p2s[8 * 128];                        // 4 KB
    const int t    = threadIdx.x;
    const int lane = t & 63;
    const int wave = t >> 6;                // 0..7
    const int wwr = wave >> 2, wwc = wave & 3;
    const int bm = blockIdx.x * 64;
    const int bn = blockIdx.y * 128;
    const int l15 = lane & 15, kb = lane >> 4;

    f32x4 acc[2][2] = {};

    int a_off[2], b_off[2];
#pragma unroll
    for (int i = 0; i < 2; ++i) a_off[i] = (wwr * 32 + i * 16 + l15) * LDSK2 + kb * 8;
#pragma unroll
    for (int j = 0; j < 2; ++j) b_off[j] = (wwc * 32 + j * 16 + l15) * LDSK2 + kb * 8;

    for (int k0 = 0; k0 < 1024; k0 += 64) {
        if (k0) __syncthreads();
        // stage A: 64 rows x 64 k = 512 f16x8 chunks, 1/thread
        {
            int row = t >> 3, g = t & 7;
            f16x8 v = *(const f16x8*)(Y + (size_t)(bm + row) * 1024 + k0 + g * 8);
            *(f16x8*)(&As[row * LDSK2 + g * 8]) = v;
        }
        // stage B: 128 cols x 64 k = 1024 chunks, 2/thread
#pragma unroll
        for (int p = 0; p < 2; ++p) {
            int e = t + p * 512;
            int row = e >> 3, g = e & 7;
            f16x8 v = *(const f16x8*)(Wcatt + (size_t)(bn + row) * 1024 + k0 + g * 8);
            *(f16x8*)(&Bs[row * LDSK2 + g * 8]) = v;
        }
        __syncthreads();

#pragma unroll
        for (int ks = 0; ks < 2; ++ks) {
            f16x8 af[2], bf[2];
#pragma unroll
            for (int i = 0; i < 2; ++i) af[i] = *(const f16x8*)(&As[a_off[i] + ks * 32]);
#pragma unroll
            for (int j = 0; j < 2; ++j) bf[j] = *(const f16x8*)(&Bs[b_off[j] + ks * 32]);
#pragma unroll
            for (int i = 0; i < 2; ++i)
#pragma unroll
                for (int j = 0; j < 2; ++j)
                    acc[i][j] = __builtin_amdgcn_mfma_f32_16x16x32_f16(af[i], bf[j], acc[i][j], 0, 0, 0);
        }
    }

    if (p2) {
#pragma unroll
        for (int p = 0; p < 2; ++p) {
            int e = t + p * 512;             // 0..1023 -> [v][c], c in 0..127
            int v = e >> 7, c = e & 127;
            p2s[e] = p2[v * 256 + bn + c];
        }
    }
    __syncthreads();

    // epilogue: C/D layout col=lane&15, row=(lane>>4)*4+q [m89-verified]
#pragma unroll
    for (int i = 0; i < 2; ++i)
#pragma unroll
        for (int q = 0; q < 4; ++q) {
            int row = bm + wwr * 32 + i * 16 + kb * 4 + q;
            float rv[2];
#pragma unroll
            for (int j = 0; j < 2; ++j) {
                int cl = wwc * 32 + j * 16 + l15;     // 0..127 within block
                float r = 0.25f * acc[i][j][q] + bias[bn + cl];
                rv[j] = r;
                if (outH) outH[(size_t)row * 256 + bn + cl] = (_Float16)fmaxf(r, 0.f);
                else      outF[(size_t)row * 256 + bn + cl] = r;
            }
            if (p2) {
                // layer-2 alpha partial dots on relu(x1) (f32-exact), this block's 128 cols
#pragma unroll
                for (int v = 0; v < 8; ++v) {
                    float ps = 0.f;
#pragma unroll
                    for (int j = 0; j < 2; ++j) {
                        int cl = wwc * 32 + j * 16 + l15;
                        ps += fmaxf(rv[j], 0.f) * p2s[v * 128 + cl];
                    }
#pragma unroll
                    for (int off = 1; off <= 8; off <<= 1) ps += __shfl_xor(ps, off);
                    if (l15 == 0) {
                        if (v < 4) atomicAdd(&asrc2[row * 4 + v], ps);
                        else       atomicAdd(&adst2[row * 4 + (v - 4)], ps);
                    }
                }
            }
        }
}

extern "C" void kernel_launch(void* const* d_in, const int* in_sizes, int n_in,
                              void* d_out, int out_size, void* d_ws, size_t ws_size,
                              hipStream_t stream) {
    const float* x0  = (const float*)d_in[0];
    const int*   ei  = (const int*)d_in[1];
    const float* W1  = (const float*)d_in[2];
    const float* as1 = (const float*)d_in[3];
    const float* ad1 = (const float*)d_in[4];
    const float* b1  = (const float*)d_in[5];
    const float* W2  = (const float*)d_in[6];
    const float* as2 = (const float*)d_in[7];
    const float* ad2 = (const float*)d_in[8];
    const float* b2  = (const float*)d_in[9];
    float* out = (float*)d_out;

    char* w = (char*)d_ws;
    _Float16* y   = (_Float16*)w; w += (size_t)NNODES * 1024 * 2;    // 17.8 MB
    _Float16* x0h = (_Float16*)w; w += (size_t)NNODES * 256 * 2;     // 4.5 MB
    _Float16* x1h = (_Float16*)w; w += (size_t)NNODES * 256 * 2;     // 4.5 MB
    _Float16* Wc1 = (_Float16*)w; w += (size_t)256 * 1024 * 2;       // 512 KB
    _Float16* Wc2 = (_Float16*)w; w += (size_t)256 * 1024 * 2;       // 512 KB
    float* pbuf   = (float*)w;    w += 16 * 256 * 4;                 // 16 KB
    float* asrcA  = (float*)w;    w += NNODES * 4 * 4;
    float* adstA  = (float*)w;    w += NNODES * 4 * 4;
    float* alphasB = (float*)w;   w += NNODES * 8 * 4;               // asrcB+adstB
    float* asrcB  = alphasB;
    float* adstB  = alphasB + NNODES * 4;
    int* cnt      = (int*)w;      w += NNODES * 4;
    int* csr      = (int*)w;      w += (size_t)NNODES * DEGCAP * 4;  // 2.2 MB

    const dim3 gemm_grid(NNODES / 64, 2);

    // K1: weights prep + zero scratch (pvec blocks) | Wcat transpose (wcat blocks)
    prep_all<<<NB_PV + NB_WC, 256, 0, stream>>>(W1, as1, ad1, W2, as2, ad2,
                                                pbuf, cnt, alphasB, Wc1, Wc2);
    // K2: CSR scatter | layer-1 alpha dots + x0->fp16
    scatter_alpha<<<NB_SC + NB_AL, 256, 0, stream>>>(ei, cnt, csr, x0, x0h, pbuf, asrcA, adstA);

    // ---- layer 1 ----
    agg_gather<<<NNODES / 4, 256, 0, stream>>>(x0h, cnt, csr, asrcA, adstA, y);
    gemm_out<<<gemm_grid, 512, 0, stream>>>(y, Wc1, b1, pbuf + 8 * 256, x1h, nullptr, asrcB, adstB);

    // ---- layer 2 ----
    agg_gather<<<NNODES / 4, 256, 0, stream>>>(x1h, cnt, csr, asrcB, adstB, y);
    gemm_out<<<gemm_grid, 512, 0, stream>>>(y, Wc2, b2, nullptr, nullptr, out, nullptr, nullptr);
}

// Round 13
// 132.016 us; speedup vs baseline: 1.2400x; 1.2400x over previous
//
#include <hip/hip_runtime.h>
#include <hip/hip_fp16.h>
#include <math.h>

// ---- problem constants (match reference) ----
#define NNODES 8704          // B*K = 512*17
#define NEDGE  139264
#define EPLUS  (NEDGE + NNODES)   // 147968 (self-loops appended)
#define NEG_SLOPE 0.2f
#define DEGCAP 64            // fixed CSR slot capacity; deg = Poisson(16)+1, P(>64) ~ 2e-14
#define LDSK   40            // gemm LDS row stride (32 + 8 fp16) -> 2-way banks

#define NB_PV  16            // prep kernel: pvec blocks
#define NB_WC  512           // prep kernel: wcat blocks (8x8x8 flattened)
#define NB_SC  ((EPLUS + 255) / 256)   // scatter blocks (579)
#define NB_AL  (NNODES / 4)  // alpha blocks (2176)

typedef _Float16 f16x8 __attribute__((ext_vector_type(8)));
typedef _Float16 f16x4 __attribute__((ext_vector_type(4)));
typedef float    f32x4 __attribute__((ext_vector_type(4)));

__device__ __forceinline__ float lrelu(float v) { return v >= 0.f ? v : NEG_SLOPE * v; }

// ---------------- K1: p-vectors (+zero cnt/alphasB) and Wcat^T, one kernel ----------------
__global__ __launch_bounds__(256) void prep_all(const float* __restrict__ W1,
                                                const float* __restrict__ as1,
                                                const float* __restrict__ ad1,
                                                const float* __restrict__ W2,
                                                const float* __restrict__ as2,
                                                const float* __restrict__ ad2,
                                                float* __restrict__ pbuf,
                                                int* __restrict__ cnt,
                                                float* __restrict__ alphasB,
                                                _Float16* __restrict__ Wc1,
                                                _Float16* __restrict__ Wc2) {
    __shared__ float tile[32][33];
    const int b = blockIdx.x;
    const int t = threadIdx.x;
    if (b < NB_PV) {
        // p[b][k] = sum_c W[k][h*256+c]*a[h][c];  b = layer*8 + sd*4 + h
        for (int i = b * 256 + t; i < NNODES; i += NB_PV * 256) cnt[i] = 0;
        for (int i = b * 256 + t; i < NNODES * 8; i += NB_PV * 256) alphasB[i] = 0.f;
        float* a_sh = &tile[0][0];
        const int layer = b >> 3, sd = (b >> 2) & 1, h = b & 3;
        const float* W  = layer ? W2 : W1;
        const float* av = layer ? (sd ? ad2 : as2) : (sd ? ad1 : as1);
        a_sh[t] = av[h * 256 + t];
        __syncthreads();
        float acc = 0.f;
        const float* Wr = W + (size_t)t * 1024 + h * 256;
#pragma unroll 8
        for (int c = 0; c < 256; ++c) acc += Wr[c] * a_sh[c];
        pbuf[b * 256 + t] = acc;
    } else {
        // Wcatt[o][h*256+k] = W[k][h*256+o] (fp16)
        const int idx = b - NB_PV;                 // 0..511
        const int k0 = (idx & 7) * 32, o0 = ((idx >> 3) & 7) * 32;
        const int z = idx >> 6;                    // 0..7
        const int layer = z >> 2, h = z & 3;
        const float* W = layer ? W2 : W1;
        _Float16* Wc   = layer ? Wc2 : Wc1;
#pragma unroll
        for (int p = 0; p < 4; ++p) {
            int e = t + p * 256; int kk = e >> 5, oo = e & 31;
            tile[kk][oo] = W[(size_t)(k0 + kk) * 1024 + h * 256 + o0 + oo];
        }
        __syncthreads();
#pragma unroll
        for (int p = 0; p < 4; ++p) {
            int e = t + p * 256; int oo = e >> 5, kk = e & 31;
            Wc[(size_t)(o0 + oo) * 1024 + h * 256 + k0 + kk] = (_Float16)tile[kk][oo];
        }
    }
}

// ---------------- K2: edge scatter + layer-1 alpha dots, one kernel ----------------
__global__ __launch_bounds__(256) void scatter_alpha(const int* __restrict__ ei,
                                                     int* __restrict__ cnt,
                                                     int* __restrict__ csr,
                                                     const float* __restrict__ xf,
                                                     _Float16* __restrict__ xh_out,
                                                     const float* __restrict__ p /* [8][256] */,
                                                     float* __restrict__ asrc,
                                                     float* __restrict__ adst) {
    const int b = blockIdx.x;
    const int t = threadIdx.x;
    if (b < NB_SC) {
        int e = b * 256 + t;
        if (e >= EPLUS) return;
        int src, dst;
        if (e < NEDGE) { src = ei[e]; dst = ei[NEDGE + e]; }
        else           { src = dst = e - NEDGE; }
        int slot = atomicAdd(&cnt[dst], 1);
        if (slot < DEGCAP) csr[dst * DEGCAP + slot] = src;
    } else {
        const int wave = t >> 6, l = t & 63;
        const int n = (b - NB_SC) * 4 + wave;
        float4 pv[8];
#pragma unroll
        for (int v = 0; v < 8; ++v) pv[v] = *(const float4*)(p + v * 256 + l * 4);
        float4 xv = *(const float4*)(xf + (size_t)n * 256 + l * 4);
        f16x4 hv = {(_Float16)xv.x, (_Float16)xv.y, (_Float16)xv.z, (_Float16)xv.w};
        *(f16x4*)(xh_out + (size_t)n * 256 + l * 4) = hv;
        float d[8];
#pragma unroll
        for (int v = 0; v < 8; ++v)
            d[v] = xv.x * pv[v].x + xv.y * pv[v].y + xv.z * pv[v].z + xv.w * pv[v].w;
#pragma unroll
        for (int off = 1; off <= 32; off <<= 1)
#pragma unroll
            for (int v = 0; v < 8; ++v) d[v] += __shfl_xor(d[v], off);
        if (l == 0) {
            *(float4*)(asrc + n * 4) = make_float4(d[0], d[1], d[2], d[3]);
            *(float4*)(adst + n * 4) = make_float4(d[4], d[5], d[6], d[7]);
        }
    }
}

// ---------------- softmax + x-gather, barrier-free: wave = node ----------------
__global__ __launch_bounds__(256) void agg_gather(const _Float16* __restrict__ xh,
                                                  const int* __restrict__ cnt,
                                                  const int* __restrict__ csr,
                                                  const float* __restrict__ asrc,
                                                  const float* __restrict__ adst,
                                                  _Float16* __restrict__ y) {
    const int w = threadIdx.x >> 6, l = threadIdx.x & 63;
    const int n = blockIdx.x * 4 + w;
    int deg = cnt[n]; if (deg > DEGCAP) deg = DEGCAP;

    float4 ad = *(const float4*)(adst + n * 4);
    int src_l = 0;
    float w0 = 0.f, w1 = 0.f, w2 = 0.f, w3 = 0.f;
    if (l < deg) {
        src_l = csr[n * DEGCAP + l];
        float4 as = *(const float4*)(asrc + src_l * 4);
        w0 = __expf(lrelu(as.x + ad.x));
        w1 = __expf(lrelu(as.y + ad.y));
        w2 = __expf(lrelu(as.z + ad.z));
        w3 = __expf(lrelu(as.w + ad.w));
    }
    float d0 = w0, d1 = w1, d2 = w2, d3 = w3;
#pragma unroll
    for (int off = 32; off >= 1; off >>= 1) {
        d0 += __shfl_xor(d0, off);
        d1 += __shfl_xor(d1, off);
        d2 += __shfl_xor(d2, off);
        d3 += __shfl_xor(d3, off);
    }
    w0 /= d0; w1 /= d1; w2 /= d2; w3 /= d3;   // normalized weight of slot l

    float acc[4][4] = {};   // [ch_sub][head]
    for (int s = 0; s < deg; ++s) {
        int src = __shfl(src_l, s);
        float u0 = __shfl(w0, s), u1 = __shfl(w1, s);
        float u2 = __shfl(w2, s), u3 = __shfl(w3, s);
        f16x4 xv = *(const f16x4*)(xh + (size_t)src * 256 + l * 4);
#pragma unroll
        for (int j = 0; j < 4; ++j) {
            float v = (float)xv[j];
            acc[j][0] += u0 * v; acc[j][1] += u1 * v;
            acc[j][2] += u2 * v; acc[j][3] += u3 * v;
        }
    }
#pragma unroll
    for (int h = 0; h < 4; ++h) {
        f16x4 pv = {(_Float16)acc[0][h], (_Float16)acc[1][h],
                    (_Float16)acc[2][h], (_Float16)acc[3][h]};
        *(f16x4*)(y + (size_t)n * 1024 + h * 256 + l * 4) = pv;
    }
}

// ---------------- output GEMM v4 (pipelined): out = 0.25 * Y @ Wcatt^T + bias ----------------
// BM=64, BN=128, BK=32; grid (136, 2) = 272 blocks (all CUs busy).
// 256 threads / 4 waves (2x2), wave tile 32x64 = 2x4 frags, 8 MFMA/step.
// LDS double-buffered; next K-tile prefetched to REGISTERS before compute, written to the
// other buffer after -> ONE barrier per K-step, global-load latency hidden under MFMA.
__global__ __launch_bounds__(256) void gemm_out(const _Float16* __restrict__ Y,
                                                const _Float16* __restrict__ Wcatt,
                                                const float* __restrict__ bias,
                                                const float* __restrict__ p2,
                                                _Float16* __restrict__ outH,  // relu+fp16 if non-null
                                                float* __restrict__ outF,
                                                float* __restrict__ asrc2,
                                                float* __restrict__ adst2) {
    __shared__ __align__(16) _Float16 As[2][64 * LDSK];    // 10.2 KB
    __shared__ __align__(16) _Float16 Bs[2][128 * LDSK];   // 20.5 KB
    __shared__ float p2s[8 * 128];                         // 4 KB
    const int t    = threadIdx.x;
    const int lane = t & 63;
    const int wave = t >> 6;
    const int wwr = wave >> 1, wwc = wave & 1;
    const int bm = blockIdx.x * 64;
    const int bn = blockIdx.y * 128;
    const int l15 = lane & 15, kb = lane >> 4;

    // staging coords: A 1 chunk/thread, B 2 chunks/thread
    const int ar = t >> 2, ag = t & 3;

    if (p2) {
#pragma unroll
        for (int p = 0; p < 4; ++p) {
            int e = t + p * 256;              // [v][c], c in 0..127
            p2s[e] = p2[(e >> 7) * 256 + bn + (e & 127)];
        }
    }

    // initial stage: K-tile 0 -> buffer 0
    {
        f16x8 va = *(const f16x8*)(Y + (size_t)(bm + ar) * 1024 + ag * 8);
        *(f16x8*)(&As[0][ar * LDSK + ag * 8]) = va;
#pragma unroll
        for (int p = 0; p < 2; ++p) {
            int e = t + p * 256;
            int row = e >> 2, g = e & 3;
            f16x8 vb = *(const f16x8*)(Wcatt + (size_t)(bn + row) * 1024 + g * 8);
            *(f16x8*)(&Bs[0][row * LDSK + g * 8]) = vb;
        }
    }
    __syncthreads();

    f32x4 acc[2][4] = {};
    int a_off[2], b_off[4];
#pragma unroll
    for (int i = 0; i < 2; ++i) a_off[i] = (wwr * 32 + i * 16 + l15) * LDSK + kb * 8;
#pragma unroll
    for (int j = 0; j < 4; ++j) b_off[j] = (wwc * 64 + j * 16 + l15) * LDSK + kb * 8;

    int cur = 0;
    for (int s = 0; s < 32; ++s) {
        // issue next tile's global loads early (latency hides under MFMA below)
        f16x8 pa; f16x8 pb[2];
        if (s < 31) {
            int k0n = (s + 1) * 32;
            pa = *(const f16x8*)(Y + (size_t)(bm + ar) * 1024 + k0n + ag * 8);
#pragma unroll
            for (int p = 0; p < 2; ++p) {
                int e = t + p * 256;
                int row = e >> 2, g = e & 3;
                pb[p] = *(const f16x8*)(Wcatt + (size_t)(bn + row) * 1024 + k0n + g * 8);
            }
        }
        // compute current tile
        f16x8 af[2], bf[4];
#pragma unroll
        for (int i = 0; i < 2; ++i) af[i] = *(const f16x8*)(&As[cur][a_off[i]]);
#pragma unroll
        for (int j = 0; j < 4; ++j) bf[j] = *(const f16x8*)(&Bs[cur][b_off[j]]);
#pragma unroll
        for (int i = 0; i < 2; ++i)
#pragma unroll
            for (int j = 0; j < 4; ++j)
                acc[i][j] = __builtin_amdgcn_mfma_f32_16x16x32_f16(af[i], bf[j], acc[i][j], 0, 0, 0);
        // write prefetched tile to the other buffer
        if (s < 31) {
            *(f16x8*)(&As[cur ^ 1][ar * LDSK + ag * 8]) = pa;
#pragma unroll
            for (int p = 0; p < 2; ++p) {
                int e = t + p * 256;
                int row = e >> 2, g = e & 3;
                *(f16x8*)(&Bs[cur ^ 1][row * LDSK + g * 8]) = pb[p];
            }
        }
        __syncthreads();
        cur ^= 1;
    }

    // epilogue: C/D layout col=lane&15, row=(lane>>4)*4+q [m89-verified]
#pragma unroll
    for (int i = 0; i < 2; ++i)
#pragma unroll
        for (int q = 0; q < 4; ++q) {
            int row = bm + wwr * 32 + i * 16 + kb * 4 + q;
            float rv[4];
#pragma unroll
            for (int j = 0; j < 4; ++j) {
                int cl = wwc * 64 + j * 16 + l15;     // 0..127 within block
                float r = 0.25f * acc[i][j][q] + bias[bn + cl];
                rv[j] = r;
                if (outH) outH[(size_t)row * 256 + bn + cl] = (_Float16)fmaxf(r, 0.f);
                else      outF[(size_t)row * 256 + bn + cl] = r;
            }
            if (p2) {
                // layer-2 alpha partial dots on relu(x1) (f32-exact), this block's 128 cols
#pragma unroll
                for (int v = 0; v < 8; ++v) {
                    float ps = 0.f;
#pragma unroll
                    for (int j = 0; j < 4; ++j) {
                        int cl = wwc * 64 + j * 16 + l15;
                        ps += fmaxf(rv[j], 0.f) * p2s[v * 128 + cl];
                    }
#pragma unroll
                    for (int off = 1; off <= 8; off <<= 1) ps += __shfl_xor(ps, off);
                    if (l15 == 0) {
                        if (v < 4) atomicAdd(&asrc2[row * 4 + v], ps);
                        else       atomicAdd(&adst2[row * 4 + (v - 4)], ps);
                    }
                }
            }
        }
}

extern "C" void kernel_launch(void* const* d_in, const int* in_sizes, int n_in,
                              void* d_out, int out_size, void* d_ws, size_t ws_size,
                              hipStream_t stream) {
    const float* x0  = (const float*)d_in[0];
    const int*   ei  = (const int*)d_in[1];
    const float* W1  = (const float*)d_in[2];
    const float* as1 = (const float*)d_in[3];
    const float* ad1 = (const float*)d_in[4];
    const float* b1  = (const float*)d_in[5];
    const float* W2  = (const float*)d_in[6];
    const float* as2 = (const float*)d_in[7];
    const float* ad2 = (const float*)d_in[8];
    const float* b2  = (const float*)d_in[9];
    float* out = (float*)d_out;

    char* w = (char*)d_ws;
    _Float16* y   = (_Float16*)w; w += (size_t)NNODES * 1024 * 2;    // 17.8 MB
    _Float16* x0h = (_Float16*)w; w += (size_t)NNODES * 256 * 2;     // 4.5 MB
    _Float16* x1h = (_Float16*)w; w += (size_t)NNODES * 256 * 2;     // 4.5 MB
    _Float16* Wc1 = (_Float16*)w; w += (size_t)256 * 1024 * 2;       // 512 KB
    _Float16* Wc2 = (_Float16*)w; w += (size_t)256 * 1024 * 2;       // 512 KB
    float* pbuf   = (float*)w;    w += 16 * 256 * 4;                 // 16 KB
    float* asrcA  = (float*)w;    w += NNODES * 4 * 4;
    float* adstA  = (float*)w;    w += NNODES * 4 * 4;
    float* alphasB = (float*)w;   w += NNODES * 8 * 4;               // asrcB+adstB
    float* asrcB  = alphasB;
    float* adstB  = alphasB + NNODES * 4;
    int* cnt      = (int*)w;      w += NNODES * 4;
    int* csr      = (int*)w;      w += (size_t)NNODES * DEGCAP * 4;  // 2.2 MB

    const dim3 gemm_grid(NNODES / 64, 2);

    // K1: weights prep + zero scratch (pvec blocks) | Wcat transpose (wcat blocks)
    prep_all<<<NB_PV + NB_WC, 256, 0, stream>>>(W1, as1, ad1, W2, as2, ad2,
                                                pbuf, cnt, alphasB, Wc1, Wc2);
    // K2: CSR scatter | layer-1 alpha dots + x0->fp16
    scatter_alpha<<<NB_SC + NB_AL, 256, 0, stream>>>(ei, cnt, csr, x0, x0h, pbuf, asrcA, adstA);

    // ---- layer 1 ----
    agg_gather<<<NNODES / 4, 256, 0, stream>>>(x0h, cnt, csr, asrcA, adstA, y);
    gemm_out<<<gemm_grid, 256, 0, stream>>>(y, Wc1, b1, pbuf + 8 * 256, x1h, nullptr, asrcB, adstB);

    // ---- layer 2 ----
    agg_gather<<<NNODES / 4, 256, 0, stream>>>(x1h, cnt, csr, asrcB, adstB, y);
    gemm_out<<<gemm_grid, 256, 0, stream>>>(y, Wc2, b2, nullptr, nullptr, out, nullptr, nullptr);
}

// Round 14
// 123.791 us; speedup vs baseline: 1.3224x; 1.0664x over previous
//
#include <hip/hip_runtime.h>
#include <hip/hip_fp16.h>
#include <math.h>

// ---- problem constants (match reference) ----
#define NNODES 8704          // B*K = 512*17
#define NEDGE  139264
#define EPLUS  (NEDGE + NNODES)   // 147968 (self-loops appended)
#define NEG_SLOPE 0.2f
#define DEGCAP 64            // fixed CSR slot capacity; deg = Poisson(16)+1, P(>64) ~ 2e-14
#define LDSK   40            // gemm LDS row stride (32 + 8 fp16) -> 2-way banks

#define NB_PV  16            // prep kernel: pvec blocks
#define NB_WC  512           // prep kernel: wcat blocks (8x8x8 flattened)
#define NB_SC  ((EPLUS + 255) / 256)   // scatter blocks (579)
#define NB_AL  (NNODES / 4)  // alpha blocks (2176)

typedef _Float16 f16x8 __attribute__((ext_vector_type(8)));
typedef _Float16 f16x4 __attribute__((ext_vector_type(4)));
typedef float    f32x4 __attribute__((ext_vector_type(4)));

__device__ __forceinline__ float lrelu(float v) { return v >= 0.f ? v : NEG_SLOPE * v; }

// ---------------- K1: p-vectors (+zero cnt/alphasB) and Wcat^T, one kernel ----------------
__global__ __launch_bounds__(256) void prep_all(const float* __restrict__ W1,
                                                const float* __restrict__ as1,
                                                const float* __restrict__ ad1,
                                                const float* __restrict__ W2,
                                                const float* __restrict__ as2,
                                                const float* __restrict__ ad2,
                                                float* __restrict__ pbuf,
                                                int* __restrict__ cnt,
                                                float* __restrict__ alphasB,
                                                _Float16* __restrict__ Wc1,
                                                _Float16* __restrict__ Wc2) {
    __shared__ float tile[32][33];
    const int b = blockIdx.x;
    const int t = threadIdx.x;
    if (b < NB_PV) {
        // p[b][k] = sum_c W[k][h*256+c]*a[h][c];  b = layer*8 + sd*4 + h
        for (int i = b * 256 + t; i < NNODES; i += NB_PV * 256) cnt[i] = 0;
        for (int i = b * 256 + t; i < NNODES * 8; i += NB_PV * 256) alphasB[i] = 0.f;
        float* a_sh = &tile[0][0];
        const int layer = b >> 3, sd = (b >> 2) & 1, h = b & 3;
        const float* W  = layer ? W2 : W1;
        const float* av = layer ? (sd ? ad2 : as2) : (sd ? ad1 : as1);
        a_sh[t] = av[h * 256 + t];
        __syncthreads();
        float acc = 0.f;
        const float* Wr = W + (size_t)t * 1024 + h * 256;
#pragma unroll 8
        for (int c = 0; c < 256; ++c) acc += Wr[c] * a_sh[c];
        pbuf[b * 256 + t] = acc;
    } else {
        // Wcatt[o][h*256+k] = W[k][h*256+o] (fp16)
        const int idx = b - NB_PV;                 // 0..511
        const int k0 = (idx & 7) * 32, o0 = ((idx >> 3) & 7) * 32;
        const int z = idx >> 6;                    // 0..7
        const int layer = z >> 2, h = z & 3;
        const float* W = layer ? W2 : W1;
        _Float16* Wc   = layer ? Wc2 : Wc1;
#pragma unroll
        for (int p = 0; p < 4; ++p) {
            int e = t + p * 256; int kk = e >> 5, oo = e & 31;
            tile[kk][oo] = W[(size_t)(k0 + kk) * 1024 + h * 256 + o0 + oo];
        }
        __syncthreads();
#pragma unroll
        for (int p = 0; p < 4; ++p) {
            int e = t + p * 256; int oo = e >> 5, kk = e & 31;
            Wc[(size_t)(o0 + oo) * 1024 + h * 256 + k0 + kk] = (_Float16)tile[kk][oo];
        }
    }
}

// ---------------- K2: edge scatter + layer-1 alpha dots, one kernel ----------------
__global__ __launch_bounds__(256) void scatter_alpha(const int* __restrict__ ei,
                                                     int* __restrict__ cnt,
                                                     int* __restrict__ csr,
                                                     const float* __restrict__ xf,
                                                     _Float16* __restrict__ xh_out,
                                                     const float* __restrict__ p /* [8][256] */,
                                                     float* __restrict__ asrc,
                                                     float* __restrict__ adst) {
    const int b = blockIdx.x;
    const int t = threadIdx.x;
    if (b < NB_SC) {
        int e = b * 256 + t;
        if (e >= EPLUS) return;
        int src, dst;
        if (e < NEDGE) { src = ei[e]; dst = ei[NEDGE + e]; }
        else           { src = dst = e - NEDGE; }
        int slot = atomicAdd(&cnt[dst], 1);
        if (slot < DEGCAP) csr[dst * DEGCAP + slot] = src;
    } else {
        const int wave = t >> 6, l = t & 63;
        const int n = (b - NB_SC) * 4 + wave;
        float4 pv[8];
#pragma unroll
        for (int v = 0; v < 8; ++v) pv[v] = *(const float4*)(p + v * 256 + l * 4);
        float4 xv = *(const float4*)(xf + (size_t)n * 256 + l * 4);
        f16x4 hv = {(_Float16)xv.x, (_Float16)xv.y, (_Float16)xv.z, (_Float16)xv.w};
        *(f16x4*)(xh_out + (size_t)n * 256 + l * 4) = hv;
        float d[8];
#pragma unroll
        for (int v = 0; v < 8; ++v)
            d[v] = xv.x * pv[v].x + xv.y * pv[v].y + xv.z * pv[v].z + xv.w * pv[v].w;
#pragma unroll
        for (int off = 1; off <= 32; off <<= 1)
#pragma unroll
            for (int v = 0; v < 8; ++v) d[v] += __shfl_xor(d[v], off);
        if (l == 0) {
            *(float4*)(asrc + n * 4) = make_float4(d[0], d[1], d[2], d[3]);
            *(float4*)(adst + n * 4) = make_float4(d[4], d[5], d[6], d[7]);
        }
    }
}

// ---------------- softmax + x-gather v3: wave = node, batch-8 load prefetch ----------------
// Lane = slot for weights; xor-butterfly denominators; gather loop double-buffers 8 x-rows
// in registers so ~560cyc of FMA covers the L2/L3 load latency. deg is wave-uniform ->
// all guards are scalar branches. Softmax without max-shift (safe range).
__global__ __launch_bounds__(256) void agg_gather(const _Float16* __restrict__ xh,
                                                  const int* __restrict__ cnt,
                                                  const int* __restrict__ csr,
                                                  const float* __restrict__ asrc,
                                                  const float* __restrict__ adst,
                                                  _Float16* __restrict__ y) {
    const int w = threadIdx.x >> 6, l = threadIdx.x & 63;
    const int n = blockIdx.x * 4 + w;
    int deg = cnt[n]; if (deg > DEGCAP) deg = DEGCAP;

    float4 ad = *(const float4*)(adst + n * 4);
    int src_l = 0;
    float w0 = 0.f, w1 = 0.f, w2 = 0.f, w3 = 0.f;
    if (l < deg) {
        src_l = csr[n * DEGCAP + l];
        float4 as = *(const float4*)(asrc + src_l * 4);
        w0 = __expf(lrelu(as.x + ad.x));
        w1 = __expf(lrelu(as.y + ad.y));
        w2 = __expf(lrelu(as.z + ad.z));
        w3 = __expf(lrelu(as.w + ad.w));
    }
    float d0 = w0, d1 = w1, d2 = w2, d3 = w3;
#pragma unroll
    for (int off = 32; off >= 1; off >>= 1) {
        d0 += __shfl_xor(d0, off);
        d1 += __shfl_xor(d1, off);
        d2 += __shfl_xor(d2, off);
        d3 += __shfl_xor(d3, off);
    }
    w0 /= d0; w1 /= d1; w2 /= d2; w3 /= d3;   // normalized weight of slot l

    const _Float16* xbase = xh + l * 4;
    float acc[4][4] = {};   // [ch_sub][head]
    f16x4 xb[8], xn[8];
    // preload batch 0
#pragma unroll
    for (int j = 0; j < 8; ++j) {
        int src = __shfl(src_l, j);
        if (j < deg) xb[j] = *(const f16x4*)(xbase + (size_t)src * 256);
    }
    for (int base = 0; base < deg; base += 8) {
        // issue next batch (independent loads, covered by the FMA block below)
#pragma unroll
        for (int j = 0; j < 8; ++j) {
            int s = base + 8 + j;
            int src = __shfl(src_l, s & 63);
            if (s < deg) xn[j] = *(const f16x4*)(xbase + (size_t)src * 256);
        }
        // consume current batch
#pragma unroll
        for (int j = 0; j < 8; ++j) {
            int s = base + j;
            if (s < deg) {
                float u0 = __shfl(w0, s), u1 = __shfl(w1, s);
                float u2 = __shfl(w2, s), u3 = __shfl(w3, s);
                f16x4 xv = xb[j];
#pragma unroll
                for (int c = 0; c < 4; ++c) {
                    float v = (float)xv[c];
                    acc[c][0] += u0 * v; acc[c][1] += u1 * v;
                    acc[c][2] += u2 * v; acc[c][3] += u3 * v;
                }
            }
        }
#pragma unroll
        for (int j = 0; j < 8; ++j) xb[j] = xn[j];
    }
#pragma unroll
    for (int h = 0; h < 4; ++h) {
        f16x4 pv = {(_Float16)acc[0][h], (_Float16)acc[1][h],
                    (_Float16)acc[2][h], (_Float16)acc[3][h]};
        *(f16x4*)(y + (size_t)n * 1024 + h * 256 + l * 4) = pv;
    }
}

// ---------------- output GEMM v5 (depth-2 pipeline): out = 0.25 * Y @ Wcatt^T + bias ----------------
// BM=64, BN=128, BK=32; grid (136, 2) = 272 blocks. 256 thr / 4 waves (2x2), wave 32x64.
// Unroll-by-2 K-loop, two register sets; each half-step issues the batch 3 tiles ahead,
// so every ds_write consumes loads issued ~2 full steps earlier (vmcnt off critical path).
// Even tiles live in LDS buffer 0, odd in buffer 1. One barrier per K-step.
__global__ __launch_bounds__(256) void gemm_out(const _Float16* __restrict__ Y,
                                                const _Float16* __restrict__ Wcatt,
                                                const float* __restrict__ bias,
                                                const float* __restrict__ p2,
                                                _Float16* __restrict__ outH,  // relu+fp16 if non-null
                                                float* __restrict__ outF,
                                                float* __restrict__ asrc2,
                                                float* __restrict__ adst2) {
    __shared__ __align__(16) _Float16 As[2][64 * LDSK];    // 10.2 KB
    __shared__ __align__(16) _Float16 Bs[2][128 * LDSK];   // 20.5 KB
    __shared__ float p2s[8 * 128];                         // 4 KB
    const int t    = threadIdx.x;
    const int lane = t & 63;
    const int wave = t >> 6;
    const int wwr = wave >> 1, wwc = wave & 1;
    const int bm = blockIdx.x * 64;
    const int bn = blockIdx.y * 128;
    const int l15 = lane & 15, kb = lane >> 4;

    // staging coords: A 1 chunk/thread (64 rows x 4 chunks), B 2 chunks/thread (128 rows x 4)
    const int ar = t >> 2, ag = t & 3;
    const int br0 = t >> 2, br1 = 64 + (t >> 2), bg = t & 3;
    const _Float16* Yb  = Y     + (size_t)(bm + ar) * 1024 + ag * 8;
    const _Float16* Wb0 = Wcatt + (size_t)(bn + br0) * 1024 + bg * 8;
    const _Float16* Wb1 = Wcatt + (size_t)(bn + br1) * 1024 + bg * 8;
    const int aw = ar * LDSK + ag * 8;
    const int bw0 = br0 * LDSK + bg * 8, bw1 = br1 * LDSK + bg * 8;

    if (p2) {
#pragma unroll
        for (int p = 0; p < 4; ++p) {
            int e = t + p * 256;              // [v][c], c in 0..127
            p2s[e] = p2[(e >> 7) * 256 + bn + (e & 127)];
        }
    }

    // prologue: tile 0 -> buffer 0; preload set0 = batch1, set1 = batch2
    {
        f16x8 a0 = *(const f16x8*)(Yb);
        f16x8 b0 = *(const f16x8*)(Wb0);
        f16x8 b1 = *(const f16x8*)(Wb1);
        *(f16x8*)(&As[0][aw])  = a0;
        *(f16x8*)(&Bs[0][bw0]) = b0;
        *(f16x8*)(&Bs[0][bw1]) = b1;
    }
    f16x8 a_s0 = *(const f16x8*)(Yb + 32);
    f16x8 bb_s0[2] = { *(const f16x8*)(Wb0 + 32), *(const f16x8*)(Wb1 + 32) };
    f16x8 a_s1 = *(const f16x8*)(Yb + 64);
    f16x8 bb_s1[2] = { *(const f16x8*)(Wb0 + 64), *(const f16x8*)(Wb1 + 64) };
    __syncthreads();

    f32x4 acc[2][4] = {};
    int a_off[2], b_off[4];
#pragma unroll
    for (int i = 0; i < 2; ++i) a_off[i] = (wwr * 32 + i * 16 + l15) * LDSK + kb * 8;
#pragma unroll
    for (int j = 0; j < 4; ++j) b_off[j] = (wwc * 64 + j * 16 + l15) * LDSK + kb * 8;

    for (int h = 0; h < 32; h += 2) {
        // ---- half A: compute tile h (buffer 0), write batch h+1 (set0) -> buffer 1,
        //              issue batch h+3 -> set0
        {
            f16x8 af[2], bf[4];
#pragma unroll
            for (int i = 0; i < 2; ++i) af[i] = *(const f16x8*)(&As[0][a_off[i]]);
#pragma unroll
            for (int j = 0; j < 4; ++j) bf[j] = *(const f16x8*)(&Bs[0][b_off[j]]);
#pragma unroll
            for (int i = 0; i < 2; ++i)
#pragma unroll
                for (int j = 0; j < 4; ++j)
                    acc[i][j] = __builtin_amdgcn_mfma_f32_16x16x32_f16(af[i], bf[j], acc[i][j], 0, 0, 0);
            *(f16x8*)(&As[1][aw])  = a_s0;
            *(f16x8*)(&Bs[1][bw0]) = bb_s0[0];
            *(f16x8*)(&Bs[1][bw1]) = bb_s0[1];
            if (h + 3 < 32) {
                int k = (h + 3) * 32;
                a_s0 = *(const f16x8*)(Yb + k);
                bb_s0[0] = *(const f16x8*)(Wb0 + k);
                bb_s0[1] = *(const f16x8*)(Wb1 + k);
            }
            __syncthreads();
        }
        // ---- half B: compute tile h+1 (buffer 1), write batch h+2 (set1) -> buffer 0,
        //              issue batch h+4 -> set1
        {
            f16x8 af[2], bf[4];
#pragma unroll
            for (int i = 0; i < 2; ++i) af[i] = *(const f16x8*)(&As[1][a_off[i]]);
#pragma unroll
            for (int j = 0; j < 4; ++j) bf[j] = *(const f16x8*)(&Bs[1][b_off[j]]);
#pragma unroll
            for (int i = 0; i < 2; ++i)
#pragma unroll
                for (int j = 0; j < 4; ++j)
                    acc[i][j] = __builtin_amdgcn_mfma_f32_16x16x32_f16(af[i], bf[j], acc[i][j], 0, 0, 0);
            if (h + 2 < 32) {
                *(f16x8*)(&As[0][aw])  = a_s1;
                *(f16x8*)(&Bs[0][bw0]) = bb_s1[0];
                *(f16x8*)(&Bs[0][bw1]) = bb_s1[1];
            }
            if (h + 4 < 32) {
                int k = (h + 4) * 32;
                a_s1 = *(const f16x8*)(Yb + k);
                bb_s1[0] = *(const f16x8*)(Wb0 + k);
                bb_s1[1] = *(const f16x8*)(Wb1 + k);
            }
            __syncthreads();
        }
    }

    // epilogue: C/D layout col=lane&15, row=(lane>>4)*4+q [m89-verified]
#pragma unroll
    for (int i = 0; i < 2; ++i)
#pragma unroll
        for (int q = 0; q < 4; ++q) {
            int row = bm + wwr * 32 + i * 16 + kb * 4 + q;
            float rv[4];
#pragma unroll
            for (int j = 0; j < 4; ++j) {
                int cl = wwc * 64 + j * 16 + l15;     // 0..127 within block
                float r = 0.25f * acc[i][j][q] + bias[bn + cl];
                rv[j] = r;
                if (outH) outH[(size_t)row * 256 + bn + cl] = (_Float16)fmaxf(r, 0.f);
                else      outF[(size_t)row * 256 + bn + cl] = r;
            }
            if (p2) {
                // layer-2 alpha partial dots on relu(x1) (f32-exact), this block's 128 cols
#pragma unroll
                for (int v = 0; v < 8; ++v) {
                    float ps = 0.f;
#pragma unroll
                    for (int j = 0; j < 4; ++j) {
                        int cl = wwc * 64 + j * 16 + l15;
                        ps += fmaxf(rv[j], 0.f) * p2s[v * 128 + cl];
                    }
#pragma unroll
                    for (int off = 1; off <= 8; off <<= 1) ps += __shfl_xor(ps, off);
                    if (l15 == 0) {
                        if (v < 4) atomicAdd(&asrc2[row * 4 + v], ps);
                        else       atomicAdd(&adst2[row * 4 + (v - 4)], ps);
                    }
                }
            }
        }
}

extern "C" void kernel_launch(void* const* d_in, const int* in_sizes, int n_in,
                              void* d_out, int out_size, void* d_ws, size_t ws_size,
                              hipStream_t stream) {
    const float* x0  = (const float*)d_in[0];
    const int*   ei  = (const int*)d_in[1];
    const float* W1  = (const float*)d_in[2];
    const float* as1 = (const float*)d_in[3];
    const float* ad1 = (const float*)d_in[4];
    const float* b1  = (const float*)d_in[5];
    const float* W2  = (const float*)d_in[6];
    const float* as2 = (const float*)d_in[7];
    const float* ad2 = (const float*)d_in[8];
    const float* b2  = (const float*)d_in[9];
    float* out = (float*)d_out;

    char* w = (char*)d_ws;
    _Float16* y   = (_Float16*)w; w += (size_t)NNODES * 1024 * 2;    // 17.8 MB
    _Float16* x0h = (_Float16*)w; w += (size_t)NNODES * 256 * 2;     // 4.5 MB
    _Float16* x1h = (_Float16*)w; w += (size_t)NNODES * 256 * 2;     // 4.5 MB
    _Float16* Wc1 = (_Float16*)w; w += (size_t)256 * 1024 * 2;       // 512 KB
    _Float16* Wc2 = (_Float16*)w; w += (size_t)256 * 1024 * 2;       // 512 KB
    float* pbuf   = (float*)w;    w += 16 * 256 * 4;                 // 16 KB
    float* asrcA  = (float*)w;    w += NNODES * 4 * 4;
    float* adstA  = (float*)w;    w += NNODES * 4 * 4;
    float* alphasB = (float*)w;   w += NNODES * 8 * 4;               // asrcB+adstB
    float* asrcB  = alphasB;
    float* adstB  = alphasB + NNODES * 4;
    int* cnt      = (int*)w;      w += NNODES * 4;
    int* csr      = (int*)w;      w += (size_t)NNODES * DEGCAP * 4;  // 2.2 MB

    const dim3 gemm_grid(NNODES / 64, 2);

    // K1: weights prep + zero scratch (pvec blocks) | Wcat transpose (wcat blocks)
    prep_all<<<NB_PV + NB_WC, 256, 0, stream>>>(W1, as1, ad1, W2, as2, ad2,
                                                pbuf, cnt, alphasB, Wc1, Wc2);
    // K2: CSR scatter | layer-1 alpha dots + x0->fp16
    scatter_alpha<<<NB_SC + NB_AL, 256, 0, stream>>>(ei, cnt, csr, x0, x0h, pbuf, asrcA, adstA);

    // ---- layer 1 ----
    agg_gather<<<NNODES / 4, 256, 0, stream>>>(x0h, cnt, csr, asrcA, adstA, y);
    gemm_out<<<gemm_grid, 256, 0, stream>>>(y, Wc1, b1, pbuf + 8 * 256, x1h, nullptr, asrcB, adstB);

    // ---- layer 2 ----
    agg_gather<<<NNODES / 4, 256, 0, stream>>>(x1h, cnt, csr, asrcB, adstB, y);
    gemm_out<<<gemm_grid, 256, 0, stream>>>(y, Wc2, b2, nullptr, nullptr, out, nullptr, nullptr);
}

// Round 15
// 122.842 us; speedup vs baseline: 1.3326x; 1.0077x over previous
//
#include <hip/hip_runtime.h>
#include <hip/hip_fp16.h>
#include <math.h>

// ---- problem constants (match reference) ----
#define NNODES 8704          // B*K = 512*17
#define NEDGE  139264
#define EPLUS  (NEDGE + NNODES)   // 147968 (self-loops appended)
#define NEG_SLOPE 0.2f
#define DEGCAP 64            // fixed CSR slot capacity; deg = Poisson(16)+1, P(>64) ~ 2e-14
#define LDSK   40            // gemm LDS row stride (32 + 8 fp16) -> 2-way banks

#define NB_PV  16            // prep kernel: pvec blocks
#define NB_WC  512           // prep kernel: wcat blocks (8x8x8 flattened)
#define NB_SC  ((EPLUS + 255) / 256)   // scatter blocks (579)
#define NB_AL  (NNODES / 4)  // alpha blocks (2176)

typedef _Float16 f16x8 __attribute__((ext_vector_type(8)));
typedef _Float16 f16x4 __attribute__((ext_vector_type(4)));
typedef float    f32x4 __attribute__((ext_vector_type(4)));

__device__ __forceinline__ float lrelu(float v) { return v >= 0.f ? v : NEG_SLOPE * v; }

// ---------------- K1: p-vectors (+zero cnt/alphasB) and Wcat^T, one kernel ----------------
__global__ __launch_bounds__(256) void prep_all(const float* __restrict__ W1,
                                                const float* __restrict__ as1,
                                                const float* __restrict__ ad1,
                                                const float* __restrict__ W2,
                                                const float* __restrict__ as2,
                                                const float* __restrict__ ad2,
                                                float* __restrict__ pbuf,
                                                int* __restrict__ cnt,
                                                float* __restrict__ alphasB,
                                                _Float16* __restrict__ Wc1,
                                                _Float16* __restrict__ Wc2) {
    __shared__ float tile[32][33];
    const int b = blockIdx.x;
    const int t = threadIdx.x;
    if (b < NB_PV) {
        // p[b][k] = sum_c W[k][h*256+c]*a[h][c];  b = layer*8 + sd*4 + h
        for (int i = b * 256 + t; i < NNODES; i += NB_PV * 256) cnt[i] = 0;
        for (int i = b * 256 + t; i < NNODES * 8; i += NB_PV * 256) alphasB[i] = 0.f;
        float* a_sh = &tile[0][0];
        const int layer = b >> 3, sd = (b >> 2) & 1, h = b & 3;
        const float* W  = layer ? W2 : W1;
        const float* av = layer ? (sd ? ad2 : as2) : (sd ? ad1 : as1);
        a_sh[t] = av[h * 256 + t];
        __syncthreads();
        float acc = 0.f;
        const float* Wr = W + (size_t)t * 1024 + h * 256;
#pragma unroll 8
        for (int c = 0; c < 256; ++c) acc += Wr[c] * a_sh[c];
        pbuf[b * 256 + t] = acc;
    } else {
        // Wcatt[o][h*256+k] = W[k][h*256+o] (fp16)
        const int idx = b - NB_PV;                 // 0..511
        const int k0 = (idx & 7) * 32, o0 = ((idx >> 3) & 7) * 32;
        const int z = idx >> 6;                    // 0..7
        const int layer = z >> 2, h = z & 3;
        const float* W = layer ? W2 : W1;
        _Float16* Wc   = layer ? Wc2 : Wc1;
#pragma unroll
        for (int p = 0; p < 4; ++p) {
            int e = t + p * 256; int kk = e >> 5, oo = e & 31;
            tile[kk][oo] = W[(size_t)(k0 + kk) * 1024 + h * 256 + o0 + oo];
        }
        __syncthreads();
#pragma unroll
        for (int p = 0; p < 4; ++p) {
            int e = t + p * 256; int oo = e >> 5, kk = e & 31;
            Wc[(size_t)(o0 + oo) * 1024 + h * 256 + k0 + kk] = (_Float16)tile[kk][oo];
        }
    }
}

// ---------------- K2: edge scatter + layer-1 alpha dots, one kernel ----------------
__global__ __launch_bounds__(256) void scatter_alpha(const int* __restrict__ ei,
                                                     int* __restrict__ cnt,
                                                     int* __restrict__ csr,
                                                     const float* __restrict__ xf,
                                                     _Float16* __restrict__ xh_out,
                                                     const float* __restrict__ p /* [8][256] */,
                                                     float* __restrict__ asrc,
                                                     float* __restrict__ adst) {
    const int b = blockIdx.x;
    const int t = threadIdx.x;
    if (b < NB_SC) {
        int e = b * 256 + t;
        if (e >= EPLUS) return;
        int src, dst;
        if (e < NEDGE) { src = ei[e]; dst = ei[NEDGE + e]; }
        else           { src = dst = e - NEDGE; }
        int slot = atomicAdd(&cnt[dst], 1);
        if (slot < DEGCAP) csr[dst * DEGCAP + slot] = src;
    } else {
        const int wave = t >> 6, l = t & 63;
        const int n = (b - NB_SC) * 4 + wave;
        float4 pv[8];
#pragma unroll
        for (int v = 0; v < 8; ++v) pv[v] = *(const float4*)(p + v * 256 + l * 4);
        float4 xv = *(const float4*)(xf + (size_t)n * 256 + l * 4);
        f16x4 hv = {(_Float16)xv.x, (_Float16)xv.y, (_Float16)xv.z, (_Float16)xv.w};
        *(f16x4*)(xh_out + (size_t)n * 256 + l * 4) = hv;
        float d[8];
#pragma unroll
        for (int v = 0; v < 8; ++v)
            d[v] = xv.x * pv[v].x + xv.y * pv[v].y + xv.z * pv[v].z + xv.w * pv[v].w;
#pragma unroll
        for (int off = 1; off <= 32; off <<= 1)
#pragma unroll
            for (int v = 0; v < 8; ++v) d[v] += __shfl_xor(d[v], off);
        if (l == 0) {
            *(float4*)(asrc + n * 4) = make_float4(d[0], d[1], d[2], d[3]);
            *(float4*)(adst + n * 4) = make_float4(d[4], d[5], d[6], d[7]);
        }
    }
}

// ---------------- softmax + x-gather v3: wave = node, batch-8 load prefetch ----------------
__global__ __launch_bounds__(256) void agg_gather(const _Float16* __restrict__ xh,
                                                  const int* __restrict__ cnt,
                                                  const int* __restrict__ csr,
                                                  const float* __restrict__ asrc,
                                                  const float* __restrict__ adst,
                                                  _Float16* __restrict__ y) {
    const int w = threadIdx.x >> 6, l = threadIdx.x & 63;
    const int n = blockIdx.x * 4 + w;
    int deg = cnt[n]; if (deg > DEGCAP) deg = DEGCAP;

    float4 ad = *(const float4*)(adst + n * 4);
    int src_l = 0;
    float w0 = 0.f, w1 = 0.f, w2 = 0.f, w3 = 0.f;
    if (l < deg) {
        src_l = csr[n * DEGCAP + l];
        float4 as = *(const float4*)(asrc + src_l * 4);
        w0 = __expf(lrelu(as.x + ad.x));
        w1 = __expf(lrelu(as.y + ad.y));
        w2 = __expf(lrelu(as.z + ad.z));
        w3 = __expf(lrelu(as.w + ad.w));
    }
    float d0 = w0, d1 = w1, d2 = w2, d3 = w3;
#pragma unroll
    for (int off = 32; off >= 1; off >>= 1) {
        d0 += __shfl_xor(d0, off);
        d1 += __shfl_xor(d1, off);
        d2 += __shfl_xor(d2, off);
        d3 += __shfl_xor(d3, off);
    }
    w0 /= d0; w1 /= d1; w2 /= d2; w3 /= d3;   // normalized weight of slot l

    const _Float16* xbase = xh + l * 4;
    float acc[4][4] = {};   // [ch_sub][head]
    f16x4 xb[8], xn[8];
#pragma unroll
    for (int j = 0; j < 8; ++j) {
        int src = __shfl(src_l, j);
        if (j < deg) xb[j] = *(const f16x4*)(xbase + (size_t)src * 256);
    }
    for (int base = 0; base < deg; base += 8) {
#pragma unroll
        for (int j = 0; j < 8; ++j) {
            int s = base + 8 + j;
            int src = __shfl(src_l, s & 63);
            if (s < deg) xn[j] = *(const f16x4*)(xbase + (size_t)src * 256);
        }
#pragma unroll
        for (int j = 0; j < 8; ++j) {
            int s = base + j;
            if (s < deg) {
                float u0 = __shfl(w0, s), u1 = __shfl(w1, s);
                float u2 = __shfl(w2, s), u3 = __shfl(w3, s);
                f16x4 xv = xb[j];
#pragma unroll
                for (int c = 0; c < 4; ++c) {
                    float v = (float)xv[c];
                    acc[c][0] += u0 * v; acc[c][1] += u1 * v;
                    acc[c][2] += u2 * v; acc[c][3] += u3 * v;
                }
            }
        }
#pragma unroll
        for (int j = 0; j < 8; ++j) xb[j] = xn[j];
    }
#pragma unroll
    for (int h = 0; h < 4; ++h) {
        f16x4 pv = {(_Float16)acc[0][h], (_Float16)acc[1][h],
                    (_Float16)acc[2][h], (_Float16)acc[3][h]};
        *(f16x4*)(y + (size_t)n * 1024 + h * 256 + l * 4) = pv;
    }
}

// ---------------- output GEMM v6 (depth-2 pipeline, BM=32): out = 0.25*Y@Wcatt^T + bias ----------------
// BM=32, BN=128, BK=32; grid (272, 2) = 544 blocks -> ~2.1 blocks/CU, 2 waves/SIMD.
// 256 thr / 4 waves (2x2), wave tile 16x64 = 1x4 frags, 4 MFMA/step.
// Depth-2 register pipeline: batches issued 3 tiles ahead; one barrier per K-step.
__global__ __launch_bounds__(256) void gemm_out(const _Float16* __restrict__ Y,
                                                const _Float16* __restrict__ Wcatt,
                                                const float* __restrict__ bias,
                                                const float* __restrict__ p2,
                                                _Float16* __restrict__ outH,  // relu+fp16 if non-null
                                                float* __restrict__ outF,
                                                float* __restrict__ asrc2,
                                                float* __restrict__ adst2) {
    __shared__ __align__(16) _Float16 As[2][32 * LDSK];    // 5.1 KB
    __shared__ __align__(16) _Float16 Bs[2][128 * LDSK];   // 20.5 KB
    __shared__ float p2s[8 * 128];                         // 4 KB
    const int t    = threadIdx.x;
    const int lane = t & 63;
    const int wave = t >> 6;
    const int wwr = wave >> 1, wwc = wave & 1;
    const int bm = blockIdx.x * 32;
    const int bn = blockIdx.y * 128;
    const int l15 = lane & 15, kb = lane >> 4;

    // staging coords: A 1 chunk/thread for t<128 (32 rows x 4 chunks), B 2 chunks/thread
    const int ar = t >> 2, ag = t & 3;            // valid for t<128
    const int br0 = t >> 2, br1 = 64 + (t >> 2), bg = t & 3;
    const _Float16* Yb  = Y     + (size_t)(bm + (ar & 31)) * 1024 + ag * 8;
    const _Float16* Wb0 = Wcatt + (size_t)(bn + br0) * 1024 + bg * 8;
    const _Float16* Wb1 = Wcatt + (size_t)(bn + br1) * 1024 + bg * 8;
    const int aw = (ar & 31) * LDSK + ag * 8;
    const int bw0 = br0 * LDSK + bg * 8, bw1 = br1 * LDSK + bg * 8;
    const bool do_a = (t < 128);

    if (p2) {
#pragma unroll
        for (int p = 0; p < 4; ++p) {
            int e = t + p * 256;              // [v][c], c in 0..127
            p2s[e] = p2[(e >> 7) * 256 + bn + (e & 127)];
        }
    }

    // prologue: tile 0 -> buffer 0; preload set0 = batch1, set1 = batch2
    {
        f16x8 b0 = *(const f16x8*)(Wb0);
        f16x8 b1 = *(const f16x8*)(Wb1);
        if (do_a) {
            f16x8 a0 = *(const f16x8*)(Yb);
            *(f16x8*)(&As[0][aw]) = a0;
        }
        *(f16x8*)(&Bs[0][bw0]) = b0;
        *(f16x8*)(&Bs[0][bw1]) = b1;
    }
    f16x8 a_s0 = {}, a_s1 = {};
    if (do_a) { a_s0 = *(const f16x8*)(Yb + 32); a_s1 = *(const f16x8*)(Yb + 64); }
    f16x8 bb_s0[2] = { *(const f16x8*)(Wb0 + 32), *(const f16x8*)(Wb1 + 32) };
    f16x8 bb_s1[2] = { *(const f16x8*)(Wb0 + 64), *(const f16x8*)(Wb1 + 64) };
    __syncthreads();

    f32x4 acc[4] = {};
    int a_off, b_off[4];
    a_off = (wwr * 16 + l15) * LDSK + kb * 8;
#pragma unroll
    for (int j = 0; j < 4; ++j) b_off[j] = (wwc * 64 + j * 16 + l15) * LDSK + kb * 8;

    for (int h = 0; h < 32; h += 2) {
        // ---- half A: compute tile h (buf 0), write batch h+1 (set0) -> buf 1, issue h+3 -> set0
        {
            f16x8 af = *(const f16x8*)(&As[0][a_off]);
            f16x8 bf[4];
#pragma unroll
            for (int j = 0; j < 4; ++j) bf[j] = *(const f16x8*)(&Bs[0][b_off[j]]);
#pragma unroll
            for (int j = 0; j < 4; ++j)
                acc[j] = __builtin_amdgcn_mfma_f32_16x16x32_f16(af, bf[j], acc[j], 0, 0, 0);
            if (do_a) *(f16x8*)(&As[1][aw]) = a_s0;
            *(f16x8*)(&Bs[1][bw0]) = bb_s0[0];
            *(f16x8*)(&Bs[1][bw1]) = bb_s0[1];
            if (h + 3 < 32) {
                int k = (h + 3) * 32;
                if (do_a) a_s0 = *(const f16x8*)(Yb + k);
                bb_s0[0] = *(const f16x8*)(Wb0 + k);
                bb_s0[1] = *(const f16x8*)(Wb1 + k);
            }
            __syncthreads();
        }
        // ---- half B: compute tile h+1 (buf 1), write batch h+2 (set1) -> buf 0, issue h+4 -> set1
        {
            f16x8 af = *(const f16x8*)(&As[1][a_off]);
            f16x8 bf[4];
#pragma unroll
            for (int j = 0; j < 4; ++j) bf[j] = *(const f16x8*)(&Bs[1][b_off[j]]);
#pragma unroll
            for (int j = 0; j < 4; ++j)
                acc[j] = __builtin_amdgcn_mfma_f32_16x16x32_f16(af, bf[j], acc[j], 0, 0, 0);
            if (h + 2 < 32) {
                if (do_a) *(f16x8*)(&As[0][aw]) = a_s1;
                *(f16x8*)(&Bs[0][bw0]) = bb_s1[0];
                *(f16x8*)(&Bs[0][bw1]) = bb_s1[1];
            }
            if (h + 4 < 32) {
                int k = (h + 4) * 32;
                if (do_a) a_s1 = *(const f16x8*)(Yb + k);
                bb_s1[0] = *(const f16x8*)(Wb0 + k);
                bb_s1[1] = *(const f16x8*)(Wb1 + k);
            }
            __syncthreads();
        }
    }

    // epilogue: C/D layout col=lane&15, row=(lane>>4)*4+q [m89-verified]
#pragma unroll
    for (int q = 0; q < 4; ++q) {
        int row = bm + wwr * 16 + kb * 4 + q;
        float rv[4];
#pragma unroll
        for (int j = 0; j < 4; ++j) {
            int cl = wwc * 64 + j * 16 + l15;     // 0..127 within block
            float r = 0.25f * acc[j][q] + bias[bn + cl];
            rv[j] = r;
            if (outH) outH[(size_t)row * 256 + bn + cl] = (_Float16)fmaxf(r, 0.f);
            else      outF[(size_t)row * 256 + bn + cl] = r;
        }
        if (p2) {
            // layer-2 alpha partial dots on relu(x1) (f32-exact), this block's 128 cols
#pragma unroll
            for (int v = 0; v < 8; ++v) {
                float ps = 0.f;
#pragma unroll
                for (int j = 0; j < 4; ++j) {
                    int cl = wwc * 64 + j * 16 + l15;
                    ps += fmaxf(rv[j], 0.f) * p2s[v * 128 + cl];
                }
#pragma unroll
                for (int off = 1; off <= 8; off <<= 1) ps += __shfl_xor(ps, off);
                if (l15 == 0) {
                    if (v < 4) atomicAdd(&asrc2[row * 4 + v], ps);
                    else       atomicAdd(&adst2[row * 4 + (v - 4)], ps);
                }
            }
        }
    }
}

extern "C" void kernel_launch(void* const* d_in, const int* in_sizes, int n_in,
                              void* d_out, int out_size, void* d_ws, size_t ws_size,
                              hipStream_t stream) {
    const float* x0  = (const float*)d_in[0];
    const int*   ei  = (const int*)d_in[1];
    const float* W1  = (const float*)d_in[2];
    const float* as1 = (const float*)d_in[3];
    const float* ad1 = (const float*)d_in[4];
    const float* b1  = (const float*)d_in[5];
    const float* W2  = (const float*)d_in[6];
    const float* as2 = (const float*)d_in[7];
    const float* ad2 = (const float*)d_in[8];
    const float* b2  = (const float*)d_in[9];
    float* out = (float*)d_out;

    char* w = (char*)d_ws;
    _Float16* y   = (_Float16*)w; w += (size_t)NNODES * 1024 * 2;    // 17.8 MB
    _Float16* x0h = (_Float16*)w; w += (size_t)NNODES * 256 * 2;     // 4.5 MB
    _Float16* x1h = (_Float16*)w; w += (size_t)NNODES * 256 * 2;     // 4.5 MB
    _Float16* Wc1 = (_Float16*)w; w += (size_t)256 * 1024 * 2;       // 512 KB
    _Float16* Wc2 = (_Float16*)w; w += (size_t)256 * 1024 * 2;       // 512 KB
    float* pbuf   = (float*)w;    w += 16 * 256 * 4;                 // 16 KB
    float* asrcA  = (float*)w;    w += NNODES * 4 * 4;
    float* adstA  = (float*)w;    w += NNODES * 4 * 4;
    float* alphasB = (float*)w;   w += NNODES * 8 * 4;               // asrcB+adstB
    float* asrcB  = alphasB;
    float* adstB  = alphasB + NNODES * 4;
    int* cnt      = (int*)w;      w += NNODES * 4;
    int* csr      = (int*)w;      w += (size_t)NNODES * DEGCAP * 4;  // 2.2 MB

    const dim3 gemm_grid(NNODES / 32, 2);

    // K1: weights prep + zero scratch (pvec blocks) | Wcat transpose (wcat blocks)
    prep_all<<<NB_PV + NB_WC, 256, 0, stream>>>(W1, as1, ad1, W2, as2, ad2,
                                                pbuf, cnt, alphasB, Wc1, Wc2);
    // K2: CSR scatter | layer-1 alpha dots + x0->fp16
    scatter_alpha<<<NB_SC + NB_AL, 256, 0, stream>>>(ei, cnt, csr, x0, x0h, pbuf, asrcA, adstA);

    // ---- layer 1 ----
    agg_gather<<<NNODES / 4, 256, 0, stream>>>(x0h, cnt, csr, asrcA, adstA, y);
    gemm_out<<<gemm_grid, 256, 0, stream>>>(y, Wc1, b1, pbuf + 8 * 256, x1h, nullptr, asrcB, adstB);

    // ---- layer 2 ----
    agg_gather<<<NNODES / 4, 256, 0, stream>>>(x1h, cnt, csr, asrcB, adstB, y);
    gemm_out<<<gemm_grid, 256, 0, stream>>>(y, Wc2, b2, nullptr, nullptr, out, nullptr, nullptr);
}